// Round 1
// baseline (402.728 us; speedup 1.0000x reference)
//
#include <hip/hip_runtime.h>
#include <cstdint>
#include <cstddef>

typedef __attribute__((ext_vector_type(8))) short short8;   // 8 bf16 (4 VGPRs)
typedef __attribute__((ext_vector_type(4))) float f32x4;    // 4 fp32 acc

#define NN 4096
#define HH 512
#define EE 65536

__device__ __forceinline__ unsigned short f2bf(float x) {
    union { float f; unsigned u; } un; un.f = x;
    unsigned r = un.u + 0x7fffu + ((un.u >> 16) & 1u);   // round-to-nearest-even
    return (unsigned short)(r >> 16);
}

// ---------------- edge counting sort (deterministic aggregation order) ----------------
__global__ void k_hist(const int* __restrict__ dst, int* __restrict__ cnt) {
    int e = blockIdx.x * 256 + threadIdx.x;
    if (e < EE) atomicAdd(&cnt[dst[e]], 1);
}

__global__ void k_scan(const int* __restrict__ cnt, int* __restrict__ starts) {
    __shared__ int sub[256];
    __shared__ int suboff[256];
    int t = threadIdx.x;
    int c[16]; int s = 0; int base = t * 16;
    for (int i = 0; i < 16; ++i) { c[i] = cnt[base + i]; s += c[i]; }
    sub[t] = s;
    __syncthreads();
    if (t == 0) { int acc = 0; for (int i = 0; i < 256; ++i) { suboff[i] = acc; acc += sub[i]; } }
    __syncthreads();
    int run = suboff[t];
    for (int i = 0; i < 16; ++i) { starts[base + i] = run; run += c[i]; }
    if (t == 255) starts[NN] = run;
}

__global__ void k_scatter(const int* __restrict__ src, const int* __restrict__ dst,
                          const int* __restrict__ starts, int* __restrict__ cursor,
                          int* __restrict__ sorted) {
    int e = blockIdx.x * 256 + threadIdx.x;
    if (e < EE) {
        int d = dst[e];
        int p = starts[d] + atomicAdd(&cursor[d], 1);
        sorted[p] = src[e];
    }
}

__global__ void k_binsort(const int* __restrict__ starts, int* __restrict__ a) {
    int d = blockIdx.x * 256 + threadIdx.x;
    if (d < NN) {
        int s = starts[d], e = starts[d + 1];
        for (int i = s + 1; i < e; ++i) {
            int v = a[i]; int j = i - 1;
            while (j >= s && a[j] > v) { a[j + 1] = a[j]; --j; }
            a[j + 1] = v;
        }
    }
}

// ---------------- f32 -> bf16 convert (vectorized) ----------------
__global__ __launch_bounds__(256) void k_cvt(const float* __restrict__ in,
                                             unsigned short* __restrict__ out, long n4) {
    long i = blockIdx.x * 256L + threadIdx.x;
    const long stride = (long)gridDim.x * 256L;
    for (; i < n4; i += stride) {
        float4 v = ((const float4*)in)[i];
        ushort4 o; o.x = f2bf(v.x); o.y = f2bf(v.y); o.z = f2bf(v.z); o.w = f2bf(v.w);
        ((ushort4*)out)[i] = o;
    }
}

// W [K][N] f32  ->  Wt [N][K] bf16
__global__ __launch_bounds__(256) void k_transcvt(const float* __restrict__ W,
                                                  unsigned short* __restrict__ Wt, int K, int N) {
    __shared__ float tile[32][33];
    const int k0 = blockIdx.x * 32, n0 = blockIdx.y * 32;
    const int tx = threadIdx.x & 31, ty = threadIdx.x >> 5;
    for (int r = ty; r < 32; r += 8)
        tile[r][tx] = W[(size_t)(k0 + r) * N + n0 + tx];
    __syncthreads();
    for (int r = ty; r < 32; r += 8)
        Wt[(size_t)(n0 + r) * K + k0 + tx] = f2bf(tile[tx][r]);
}

// ---------------- bf16 MFMA GEMM: C = A[M][K] @ Bt[N][K]^T, 128x128 tile, BK=32 ----------------
// EPI 0: store raw f32. EPI 1: +bias, BN, ReLU -> bf16. EPI 2: +bias, BN, ReLU, BN, ReLU -> f32.
template<int EPI>
__global__ __launch_bounds__(256) void k_gemm(
    const unsigned short* __restrict__ A, const unsigned short* __restrict__ Bt,
    int M, int N, int K,
    const float* __restrict__ bias,
    const float* __restrict__ g1p, const float* __restrict__ b1p,
    const float* __restrict__ m1p, const float* __restrict__ v1p,
    const float* __restrict__ g2p, const float* __restrict__ b2p,
    const float* __restrict__ m2p, const float* __restrict__ v2p,
    float* __restrict__ outf, unsigned short* __restrict__ outb)
{
    __shared__ alignas(16) unsigned short As[128 * 32];
    __shared__ alignas(16) unsigned short Bs[128 * 32];
    const int t = threadIdx.x;
    const int lane = t & 63, w = t >> 6;
    const int wr = w >> 1, wc = w & 1;
    const int l15 = lane & 15, l4 = lane >> 4;
    const int m0 = blockIdx.x * 128, n0 = blockIdx.y * 128;

    f32x4 acc[4][4];
#pragma unroll
    for (int i = 0; i < 4; ++i)
#pragma unroll
        for (int j = 0; j < 4; ++j) acc[i][j] = (f32x4){0.f, 0.f, 0.f, 0.f};

    const int r0 = t >> 2, s0 = (t & 3) * 8;   // 512 16B chunks per tile, 2 per thread
    const unsigned short* Ab = A + (size_t)m0 * K;
    const unsigned short* Bb = Bt + (size_t)n0 * K;

    uint4 ra0 = *(const uint4*)(Ab + (size_t)r0 * K + s0);
    uint4 ra1 = *(const uint4*)(Ab + (size_t)(r0 + 64) * K + s0);
    uint4 rb0 = *(const uint4*)(Bb + (size_t)r0 * K + s0);
    uint4 rb1 = *(const uint4*)(Bb + (size_t)(r0 + 64) * K + s0);

    const int nk = K >> 5;
    for (int kt = 0; kt < nk; ++kt) {
        __syncthreads();
        ((uint4*)As)[t] = ra0; ((uint4*)As)[t + 256] = ra1;
        ((uint4*)Bs)[t] = rb0; ((uint4*)Bs)[t + 256] = rb1;
        __syncthreads();
        if (kt + 1 < nk) {
            const int kn = (kt + 1) << 5;
            ra0 = *(const uint4*)(Ab + (size_t)r0 * K + kn + s0);
            ra1 = *(const uint4*)(Ab + (size_t)(r0 + 64) * K + kn + s0);
            rb0 = *(const uint4*)(Bb + (size_t)r0 * K + kn + s0);
            rb1 = *(const uint4*)(Bb + (size_t)(r0 + 64) * K + kn + s0);
        }
        short8 aF[4], bF[4];
#pragma unroll
        for (int i = 0; i < 4; ++i)
            aF[i] = *(const short8*)(As + (wr * 64 + i * 16 + l15) * 32 + 8 * l4);
#pragma unroll
        for (int j = 0; j < 4; ++j)
            bF[j] = *(const short8*)(Bs + (wc * 64 + j * 16 + l15) * 32 + 8 * l4);
#pragma unroll
        for (int i = 0; i < 4; ++i)
#pragma unroll
            for (int j = 0; j < 4; ++j)
                acc[i][j] = __builtin_amdgcn_mfma_f32_16x16x32_bf16(aF[i], bF[j], acc[i][j], 0, 0, 0);
    }

    const int mrow = m0 + wr * 64;
    const int ncol = n0 + wc * 64;
#pragma unroll
    for (int j = 0; j < 4; ++j) {
        const int cg = ncol + j * 16 + l15;
        float bi = 0.f, sc1 = 1.f, sh1 = 0.f, sc2 = 1.f, sh2 = 0.f;
        if (EPI >= 1) {
            bi = bias[cg];
            sc1 = rsqrtf(v1p[cg] + 1e-5f) * g1p[cg];
            sh1 = b1p[cg] - m1p[cg] * sc1;
        }
        if (EPI == 2) {
            sc2 = rsqrtf(v2p[cg] + 1e-5f) * g2p[cg];
            sh2 = b2p[cg] - m2p[cg] * sc2;
        }
#pragma unroll
        for (int i = 0; i < 4; ++i) {
#pragma unroll
            for (int r = 0; r < 4; ++r) {
                const int rg = mrow + i * 16 + l4 * 4 + r;
                float x = acc[i][j][r];
                if (EPI == 0) {
                    outf[(size_t)rg * N + cg] = x;
                } else if (EPI == 1) {
                    x = fmaxf((x + bi) * sc1 + sh1, 0.f);
                    outb[(size_t)rg * N + cg] = f2bf(x);
                } else {
                    x = fmaxf((x + bi) * sc1 + sh1, 0.f);
                    x = fmaxf(x * sc2 + sh2, 0.f);
                    outf[(size_t)rg * N + cg] = x;
                }
            }
        }
    }
}

// ---------------- edge aggregation (gather-sum over sorted in-edges) ----------------
// layer 0: xb = bf16(ReLU(BN((1+eps)*G0[d] + sum G0[src] + bias)))
__global__ __launch_bounds__(128) void k_agg0(
    const float* __restrict__ G0, const int* __restrict__ starts, const int* __restrict__ sorted,
    const float* __restrict__ epsp, const float* __restrict__ bias,
    const float* __restrict__ bg, const float* __restrict__ bb,
    const float* __restrict__ bm, const float* __restrict__ bv,
    unsigned short* __restrict__ outb)
{
    const int d = blockIdx.x, t = threadIdx.x;
    const float ep = 1.0f + epsp[0];
    float4 own = ((const float4*)(G0 + (size_t)d * HH))[t];
    float sx = 0.f, sy = 0.f, sz = 0.f, sw = 0.f;
    const int e0 = starts[d], e1 = starts[d + 1];
    for (int i = e0; i < e1; ++i) {
        float4 x = ((const float4*)(G0 + (size_t)sorted[i] * HH))[t];
        sx += x.x; sy += x.y; sz += x.z; sw += x.w;
    }
    float4 bi = ((const float4*)bias)[t];
    float4 g4 = ((const float4*)bg)[t];
    float4 b4 = ((const float4*)bb)[t];
    float4 m4 = ((const float4*)bm)[t];
    float4 v4 = ((const float4*)bv)[t];
    float x0 = ep * own.x + sx + bi.x;
    float x1 = ep * own.y + sy + bi.y;
    float x2 = ep * own.z + sz + bi.z;
    float x3 = ep * own.w + sw + bi.w;
    x0 = fmaxf((x0 - m4.x) * rsqrtf(v4.x + 1e-5f) * g4.x + b4.x, 0.f);
    x1 = fmaxf((x1 - m4.y) * rsqrtf(v4.y + 1e-5f) * g4.y + b4.y, 0.f);
    x2 = fmaxf((x2 - m4.z) * rsqrtf(v4.z + 1e-5f) * g4.z + b4.z, 0.f);
    x3 = fmaxf((x3 - m4.w) * rsqrtf(v4.w + 1e-5f) * g4.w + b4.w, 0.f);
    ushort4 o; o.x = f2bf(x0); o.y = f2bf(x1); o.z = f2bf(x2); o.w = f2bf(x3);
    ((ushort4*)(outb + (size_t)d * HH))[t] = o;
}

// hidden layers: xb = bf16((1+eps)*h[d] + sum h[src])
__global__ __launch_bounds__(128) void k_aggL(
    const float* __restrict__ hsrc, const int* __restrict__ starts, const int* __restrict__ sorted,
    const float* __restrict__ epsp, unsigned short* __restrict__ outb)
{
    const int d = blockIdx.x, t = threadIdx.x;
    const float ep = 1.0f + epsp[0];
    float4 own = ((const float4*)(hsrc + (size_t)d * HH))[t];
    float sx = 0.f, sy = 0.f, sz = 0.f, sw = 0.f;
    const int e0 = starts[d], e1 = starts[d + 1];
    for (int i = e0; i < e1; ++i) {
        float4 x = ((const float4*)(hsrc + (size_t)sorted[i] * HH))[t];
        sx += x.x; sy += x.y; sz += x.z; sw += x.w;
    }
    ushort4 o;
    o.x = f2bf(ep * own.x + sx);
    o.y = f2bf(ep * own.y + sy);
    o.z = f2bf(ep * own.z + sz);
    o.w = f2bf(ep * own.w + sw);
    ((ushort4*)(outb + (size_t)d * HH))[t] = o;
}

// ---------------- readout: partial dot products v . W[:,c], c in {0,1} ----------------
__global__ __launch_bounds__(256) void k_dot2(const float* __restrict__ v, const float* __restrict__ w,
                                              long n4, float* __restrict__ part) {
    long i = blockIdx.x * 256L + threadIdx.x;
    const long stride = (long)gridDim.x * 256L;
    float a0 = 0.f, a1 = 0.f;
    for (; i < n4; i += stride) {
        float4 x = ((const float4*)v)[i];
        float4 wA = ((const float4*)w)[2 * i];
        float4 wB = ((const float4*)w)[2 * i + 1];
        a0 += x.x * wA.x + x.y * wA.z + x.z * wB.x + x.w * wB.z;
        a1 += x.x * wA.y + x.y * wA.w + x.z * wB.y + x.w * wB.w;
    }
    __shared__ float s0[256], s1[256];
    int t = threadIdx.x;
    s0[t] = a0; s1[t] = a1;
    __syncthreads();
    for (int s = 128; s > 0; s >>= 1) {
        if (t < s) { s0[t] += s0[t + s]; s1[t] += s1[t + s]; }
        __syncthreads();
    }
    if (t == 0) { part[2 * blockIdx.x] = s0[0]; part[2 * blockIdx.x + 1] = s1[0]; }
}

__global__ __launch_bounds__(256) void k_final(const float* __restrict__ part, int nslot,
                                               const float* __restrict__ bp0, const float* __restrict__ bpR,
                                               float* __restrict__ out) {
    __shared__ float s0[256], s1[256];
    int t = threadIdx.x;
    float a0 = 0.f, a1 = 0.f;
    for (int i = t; i < nslot; i += 256) { a0 += part[2 * i]; a1 += part[2 * i + 1]; }
    s0[t] = a0; s1[t] = a1;
    __syncthreads();
    for (int s = 128; s > 0; s >>= 1) {
        if (t < s) { s0[t] += s0[t + s]; s1[t] += s1[t + s]; }
        __syncthreads();
    }
    if (t == 0) {
        out[0] = s0[0] + bp0[0] + bpR[0] + bpR[2] + bpR[4] + bpR[6];
        out[1] = s1[0] + bp0[1] + bpR[1] + bpR[3] + bpR[5] + bpR[7];
    }
}

extern "C" void kernel_launch(void* const* d_in, const int* in_sizes, int n_in,
                              void* d_out, int out_size, void* d_ws, size_t ws_size,
                              hipStream_t stream)
{
    const float* feat = (const float*)d_in[0];
    const int*   esrc = (const int*)d_in[1];
    const int*   edst = (const int*)d_in[2];
    const float* eps0 = (const float*)d_in[3];
    const float* W0a  = (const float*)d_in[4];
    const float* b0a  = (const float*)d_in[5];
    const float* W0b  = (const float*)d_in[6];
    const float* b0b  = (const float*)d_in[7];
    const float* bn0a_g = (const float*)d_in[8];
    const float* bn0a_b = (const float*)d_in[9];
    const float* bn0a_m = (const float*)d_in[10];
    const float* bn0a_v = (const float*)d_in[11];
    const float* bnA0_g = (const float*)d_in[12];
    const float* bnA0_b = (const float*)d_in[13];
    const float* bnA0_m = (const float*)d_in[14];
    const float* bnA0_v = (const float*)d_in[15];
    const float* bnO0_g = (const float*)d_in[16];
    const float* bnO0_b = (const float*)d_in[17];
    const float* bnO0_m = (const float*)d_in[18];
    const float* bnO0_v = (const float*)d_in[19];
    const float* epsR = (const float*)d_in[20];
    const float* WRa  = (const float*)d_in[21];
    const float* bRa  = (const float*)d_in[22];
    const float* WRb  = (const float*)d_in[23];
    const float* bRb  = (const float*)d_in[24];
    const float* bnRa_g = (const float*)d_in[25];
    const float* bnRa_b = (const float*)d_in[26];
    const float* bnRa_m = (const float*)d_in[27];
    const float* bnRa_v = (const float*)d_in[28];
    const float* bnAR_g = (const float*)d_in[29];
    const float* bnAR_b = (const float*)d_in[30];
    const float* bnAR_m = (const float*)d_in[31];
    const float* bnAR_v = (const float*)d_in[32];
    const float* bnOR_g = (const float*)d_in[33];
    const float* bnOR_b = (const float*)d_in[34];
    const float* bnOR_m = (const float*)d_in[35];
    const float* bnOR_v = (const float*)d_in[36];
    const float* Wp0 = (const float*)d_in[37];
    const float* bp0 = (const float*)d_in[38];
    const float* WpR = (const float*)d_in[39];
    const float* bpR = (const float*)d_in[40];
    float* out = (float*)d_out;

    char* ws = (char*)d_ws;
    const size_t MB = 1024 * 1024;
    int*   cnt    = (int*)(ws + 0x00000);
    int*   starts = (int*)(ws + 0x10000);
    int*   cursor = (int*)(ws + 0x20000);
    int*   sorted = (int*)(ws + 0x30000);     // 256 KiB
    float* part   = (float*)(ws + 0x70000);   // 2048*2 f32
    unsigned short* featb = (unsigned short*)(ws + 1 * MB);    // [4096][4096] bf16, 32 MiB
    unsigned short* w0at  = (unsigned short*)(ws + 33 * MB);   // [512][4096] bf16, 4 MiB
    unsigned short* wt    = (unsigned short*)(ws + 37 * MB);   // 7 x [512][512] bf16
    float* G0 = (float*)(ws + 41 * MB);                        // [4096][512] f32
    unsigned short* xb = (unsigned short*)(ws + 49 * MB);      // [4096][512] bf16
    unsigned short* yb = (unsigned short*)(ws + 53 * MB);      // [4096][512] bf16
    float* h = (float*)(ws + 57 * MB);                         // 4 x [4096][512] f32

    // ---- edge sort ----
    hipMemsetAsync(ws, 0, 0x30000, stream);
    k_hist<<<EE / 256, 256, 0, stream>>>(edst, cnt);
    k_scan<<<1, 256, 0, stream>>>(cnt, starts);
    k_scatter<<<EE / 256, 256, 0, stream>>>(esrc, edst, starts, cursor, sorted);
    k_binsort<<<NN / 256, 256, 0, stream>>>(starts, sorted);

    // ---- precision prep ----
    k_cvt<<<2048, 256, 0, stream>>>(feat, featb, (long)NN * NN / 4);
    k_transcvt<<<dim3(NN / 32, HH / 32), 256, 0, stream>>>(W0a, w0at, NN, HH);
    k_transcvt<<<dim3(HH / 32, HH / 32), 256, 0, stream>>>(W0b, wt, HH, HH);
    for (int i = 0; i < 3; ++i) {
        k_transcvt<<<dim3(HH / 32, HH / 32), 256, 0, stream>>>(
            WRa + (size_t)i * HH * HH, wt + (size_t)(1 + i) * HH * HH, HH, HH);
        k_transcvt<<<dim3(HH / 32, HH / 32), 256, 0, stream>>>(
            WRb + (size_t)i * HH * HH, wt + (size_t)(4 + i) * HH * HH, HH, HH);
    }

    const dim3 ggrid(NN / 128, HH / 128);
    // ---- layer 0 (reassociated: G0 = feat@W0a first, then aggregate) ----
    k_gemm<0><<<ggrid, 256, 0, stream>>>(featb, w0at, NN, HH, NN,
        nullptr, nullptr, nullptr, nullptr, nullptr, nullptr, nullptr, nullptr, nullptr,
        G0, nullptr);
    k_agg0<<<NN, 128, 0, stream>>>(G0, starts, sorted, eps0, b0a,
                                   bn0a_g, bn0a_b, bn0a_m, bn0a_v, xb);
    k_gemm<2><<<ggrid, 256, 0, stream>>>(xb, wt, NN, HH, HH,
        b0b, bnA0_g, bnA0_b, bnA0_m, bnA0_v, bnO0_g, bnO0_b, bnO0_m, bnO0_v,
        h, nullptr);

    // ---- layers 1..3 ----
    for (int i = 0; i < 3; ++i) {
        const float* hp = h + (size_t)i * NN * HH;
        float* hn = h + (size_t)(i + 1) * NN * HH;
        k_aggL<<<NN, 128, 0, stream>>>(hp, starts, sorted, epsR + i, xb);
        k_gemm<1><<<ggrid, 256, 0, stream>>>(xb, wt + (size_t)(1 + i) * HH * HH, NN, HH, HH,
            bRa + (size_t)i * HH,
            bnRa_g + (size_t)i * HH, bnRa_b + (size_t)i * HH, bnRa_m + (size_t)i * HH, bnRa_v + (size_t)i * HH,
            nullptr, nullptr, nullptr, nullptr,
            nullptr, yb);
        k_gemm<2><<<ggrid, 256, 0, stream>>>(yb, wt + (size_t)(4 + i) * HH * HH, NN, HH, HH,
            bRb + (size_t)i * HH,
            bnAR_g + (size_t)i * HH, bnAR_b + (size_t)i * HH, bnAR_m + (size_t)i * HH, bnAR_v + (size_t)i * HH,
            bnOR_g + (size_t)i * HH, bnOR_b + (size_t)i * HH, bnOR_m + (size_t)i * HH, bnOR_v + (size_t)i * HH,
            hn, nullptr);
    }

    // ---- jumping-knowledge readout ----
    k_dot2<<<1024, 256, 0, stream>>>(feat, Wp0, (long)NN * NN / 4, part);
    for (int i = 0; i < 4; ++i)
        k_dot2<<<256, 256, 0, stream>>>(h + (size_t)i * NN * HH,
                                        WpR + (size_t)i * NN * HH * 2,
                                        (long)NN * HH / 4, part + 2 * (1024 + i * 256));
    k_final<<<1, 256, 0, stream>>>(part, 1024 + 4 * 256, bp0, bpR, out);
}

// Round 2
// 335.394 us; speedup vs baseline: 1.2008x; 1.2008x over previous
//
#include <hip/hip_runtime.h>
#include <cstdint>
#include <cstddef>

typedef __attribute__((ext_vector_type(8))) short short8;   // 8 bf16 (4 VGPRs)
typedef __attribute__((ext_vector_type(4))) float f32x4;    // 4 fp32 acc

#define NN 4096
#define HH 512
#define EE 65536

// async global->LDS, 16B per lane (dest must be linear: base + lane*16)
#define GLOAD(gp, lp) __builtin_amdgcn_global_load_lds( \
    (const __attribute__((address_space(1))) void*)(gp), \
    (__attribute__((address_space(3))) void*)(lp), 16, 0, 0)

__device__ __forceinline__ unsigned short f2bf(float x) {
    union { float f; unsigned u; } un; un.f = x;
    unsigned r = un.u + 0x7fffu + ((un.u >> 16) & 1u);   // round-to-nearest-even
    return (unsigned short)(r >> 16);
}

// ---------------- edge counting sort (deterministic aggregation order) ----------------
__global__ void k_hist(const int* __restrict__ dst, int* __restrict__ cnt) {
    int e = blockIdx.x * 256 + threadIdx.x;
    if (e < EE) atomicAdd(&cnt[dst[e]], 1);
}

__global__ void k_scan(const int* __restrict__ cnt, int* __restrict__ starts) {
    __shared__ int sub[256];
    __shared__ int suboff[256];
    int t = threadIdx.x;
    int c[16]; int s = 0; int base = t * 16;
    for (int i = 0; i < 16; ++i) { c[i] = cnt[base + i]; s += c[i]; }
    sub[t] = s;
    __syncthreads();
    if (t == 0) { int acc = 0; for (int i = 0; i < 256; ++i) { suboff[i] = acc; acc += sub[i]; } }
    __syncthreads();
    int run = suboff[t];
    for (int i = 0; i < 16; ++i) { starts[base + i] = run; run += c[i]; }
    if (t == 255) starts[NN] = run;
}

__global__ void k_scatter(const int* __restrict__ src, const int* __restrict__ dst,
                          const int* __restrict__ starts, int* __restrict__ cursor,
                          int* __restrict__ sorted) {
    int e = blockIdx.x * 256 + threadIdx.x;
    if (e < EE) {
        int d = dst[e];
        int p = starts[d] + atomicAdd(&cursor[d], 1);
        sorted[p] = src[e];
    }
}

__global__ void k_binsort(const int* __restrict__ starts, int* __restrict__ a) {
    int d = blockIdx.x * 256 + threadIdx.x;
    if (d < NN) {
        int s = starts[d], e = starts[d + 1];
        for (int i = s + 1; i < e; ++i) {
            int v = a[i]; int j = i - 1;
            while (j >= s && a[j] > v) { a[j + 1] = a[j]; --j; }
            a[j + 1] = v;
        }
    }
}

// ---------------- fused: feat f32 -> bf16 convert + feat . Wp0 partial dot ----------------
__global__ __launch_bounds__(256) void k_cvtdot0(const float* __restrict__ feat,
                                                 const float* __restrict__ w,
                                                 unsigned short* __restrict__ featb,
                                                 float* __restrict__ part) {
    const long n4 = (long)NN * NN / 4;
    long i = blockIdx.x * 256L + threadIdx.x;
    const long stride = (long)gridDim.x * 256L;
    float a0 = 0.f, a1 = 0.f;
    for (; i < n4; i += stride) {
        float4 v = ((const float4*)feat)[i];
        ushort4 o; o.x = f2bf(v.x); o.y = f2bf(v.y); o.z = f2bf(v.z); o.w = f2bf(v.w);
        ((ushort4*)featb)[i] = o;
        float4 wA = ((const float4*)w)[2 * i];
        float4 wB = ((const float4*)w)[2 * i + 1];
        a0 += v.x * wA.x + v.y * wA.z + v.z * wB.x + v.w * wB.z;
        a1 += v.x * wA.y + v.y * wA.w + v.z * wB.y + v.w * wB.w;
    }
    __shared__ float s0[256], s1[256];
    int t = threadIdx.x;
    s0[t] = a0; s1[t] = a1;
    __syncthreads();
    for (int s = 128; s > 0; s >>= 1) {
        if (t < s) { s0[t] += s0[t + s]; s1[t] += s1[t + s]; }
        __syncthreads();
    }
    if (t == 0) { part[2 * blockIdx.x] = s0[0]; part[2 * blockIdx.x + 1] = s1[0]; }
}

// W [K][N] f32  ->  Wt [N][K] bf16   (single large weight)
__global__ __launch_bounds__(256) void k_transcvt(const float* __restrict__ W,
                                                  unsigned short* __restrict__ Wt, int K, int N) {
    __shared__ float tile[32][33];
    const int k0 = blockIdx.x * 32, n0 = blockIdx.y * 32;
    const int tx = threadIdx.x & 31, ty = threadIdx.x >> 5;
    for (int r = ty; r < 32; r += 8)
        tile[r][tx] = W[(size_t)(k0 + r) * N + n0 + tx];
    __syncthreads();
    for (int r = ty; r < 32; r += 8)
        Wt[(size_t)(n0 + r) * K + k0 + tx] = f2bf(tile[tx][r]);
}

// batched 512x512 transposes: z=0 -> W0b, z=1..3 -> WRa[z-1], z=4..6 -> WRb[z-4]
__global__ __launch_bounds__(256) void k_transcvt7(const float* __restrict__ W0b,
                                                   const float* __restrict__ WRa,
                                                   const float* __restrict__ WRb,
                                                   unsigned short* __restrict__ wt) {
    __shared__ float tile[32][33];
    const int z = blockIdx.z;
    const float* W = (z == 0) ? W0b
                   : (z < 4) ? WRa + (size_t)(z - 1) * HH * HH
                             : WRb + (size_t)(z - 4) * HH * HH;
    unsigned short* Wt = wt + (size_t)z * HH * HH;
    const int k0 = blockIdx.x * 32, n0 = blockIdx.y * 32;
    const int tx = threadIdx.x & 31, ty = threadIdx.x >> 5;
    for (int r = ty; r < 32; r += 8)
        tile[r][tx] = W[(size_t)(k0 + r) * HH + n0 + tx];
    __syncthreads();
    for (int r = ty; r < 32; r += 8)
        Wt[(size_t)(n0 + r) * HH + k0 + tx] = f2bf(tile[tx][r]);
}

// ---------------- bf16 MFMA GEMM: C = A[M][K] @ Bt[N][K]^T ----------------
// Tile 128 x BN, BK=32, double-buffered LDS via global_load_lds, split-K = gridDim.z.
// EPI 0: store raw f32 partial (offset by z*M*N). EPI 1: +bias,BN,ReLU -> bf16.
// EPI 2: +bias,BN,ReLU,BN,ReLU -> f32.
template<int EPI, int BN>
__global__ __launch_bounds__(256) void k_gemm(
    const unsigned short* __restrict__ A, const unsigned short* __restrict__ Bt,
    int M, int N, int K,
    const float* __restrict__ bias,
    const float* __restrict__ g1p, const float* __restrict__ b1p,
    const float* __restrict__ m1p, const float* __restrict__ v1p,
    const float* __restrict__ g2p, const float* __restrict__ b2p,
    const float* __restrict__ m2p, const float* __restrict__ v2p,
    float* __restrict__ outf, unsigned short* __restrict__ outb)
{
    __shared__ alignas(16) unsigned short As[2][128 * 32];
    __shared__ alignas(16) unsigned short Bs[2][BN * 32];
    const int t = threadIdx.x;
    const int lane = t & 63, w = t >> 6;
    const int wr = w >> 1, wc = w & 1;
    const int l15 = lane & 15, l4 = lane >> 4;
    const int m0 = blockIdx.x * 128, n0 = blockIdx.y * BN;
    constexpr int NJ = BN / 32;          // 16-col frags per wave in N
    constexpr int WCW = BN / 2;          // wave column width

    f32x4 acc[4][NJ];
#pragma unroll
    for (int i = 0; i < 4; ++i)
#pragma unroll
        for (int j = 0; j < NJ; ++j) acc[i][j] = (f32x4){0.f, 0.f, 0.f, 0.f};

    const int Kc = K / gridDim.z;
    const int kbase = blockIdx.z * Kc;
    const unsigned short* Ab = A + (size_t)m0 * K + kbase;
    const unsigned short* Bb = Bt + (size_t)n0 * K + kbase;
    // per-thread 16B-chunk source addresses (chunk id t -> row t>>2, col (t&3)*8)
    const unsigned short* ga0 = Ab + (size_t)(t >> 2) * K + (t & 3) * 8;
    const unsigned short* ga1 = ga0 + (size_t)64 * K;
    const unsigned short* gb0 = Bb + (size_t)(t >> 2) * K + (t & 3) * 8;
    const unsigned short* gb1 = gb0 + (size_t)64 * K;

    auto stage = [&](int kt, int buf) {
        const int ko = kt * 32;
        GLOAD(ga0 + ko, &As[buf][t * 8]);
        GLOAD(ga1 + ko, &As[buf][(t + 256) * 8]);
        GLOAD(gb0 + ko, &Bs[buf][t * 8]);
        if constexpr (BN == 128) {
            GLOAD(gb1 + ko, &Bs[buf][(t + 256) * 8]);
        }
    };

    const int nk = Kc >> 5;
    stage(0, 0);
    __syncthreads();                     // drains vmcnt: buf0 ready
    for (int kt = 0; kt < nk; ++kt) {
        const int cur = kt & 1;
        if (kt + 1 < nk) stage(kt + 1, cur ^ 1);
        short8 aF[4], bF[NJ];
#pragma unroll
        for (int i = 0; i < 4; ++i)
            aF[i] = *(const short8*)(&As[cur][(wr * 64 + i * 16 + l15) * 32 + 8 * l4]);
#pragma unroll
        for (int j = 0; j < NJ; ++j)
            bF[j] = *(const short8*)(&Bs[cur][(wc * WCW + j * 16 + l15) * 32 + 8 * l4]);
#pragma unroll
        for (int i = 0; i < 4; ++i)
#pragma unroll
            for (int j = 0; j < NJ; ++j)
                acc[i][j] = __builtin_amdgcn_mfma_f32_16x16x32_bf16(aF[i], bF[j], acc[i][j], 0, 0, 0);
        __syncthreads();                 // drains vmcnt: next buffer ready, all reads done
    }

    const int mrow = m0 + wr * 64;
    float* op = outf + (EPI == 0 ? (size_t)blockIdx.z * M * N : 0);
#pragma unroll
    for (int j = 0; j < NJ; ++j) {
        const int cg = n0 + wc * WCW + j * 16 + l15;
        float bi = 0.f, sc1 = 1.f, sh1 = 0.f, sc2 = 1.f, sh2 = 0.f;
        if (EPI >= 1) {
            bi = bias[cg];
            sc1 = rsqrtf(v1p[cg] + 1e-5f) * g1p[cg];
            sh1 = b1p[cg] - m1p[cg] * sc1;
        }
        if (EPI == 2) {
            sc2 = rsqrtf(v2p[cg] + 1e-5f) * g2p[cg];
            sh2 = b2p[cg] - m2p[cg] * sc2;
        }
#pragma unroll
        for (int i = 0; i < 4; ++i) {
#pragma unroll
            for (int r = 0; r < 4; ++r) {
                const int rg = mrow + i * 16 + l4 * 4 + r;
                float x = acc[i][j][r];
                if (EPI == 0) {
                    op[(size_t)rg * N + cg] = x;
                } else if (EPI == 1) {
                    x = fmaxf((x + bi) * sc1 + sh1, 0.f);
                    outb[(size_t)rg * N + cg] = f2bf(x);
                } else {
                    x = fmaxf((x + bi) * sc1 + sh1, 0.f);
                    x = fmaxf(x * sc2 + sh2, 0.f);
                    op[(size_t)rg * N + cg] = x;
                }
            }
        }
    }
}

// sum 4 split-K partials -> G0
__global__ __launch_bounds__(256) void k_red4(const float* __restrict__ p, float* __restrict__ G0) {
    const long S = (long)NN * HH / 4;
    long i = blockIdx.x * 256L + threadIdx.x;
    float4 a = ((const float4*)p)[i];
    float4 b = ((const float4*)p)[i + S];
    float4 c = ((const float4*)p)[i + 2 * S];
    float4 d = ((const float4*)p)[i + 3 * S];
    float4 o;
    o.x = (a.x + b.x) + (c.x + d.x);
    o.y = (a.y + b.y) + (c.y + d.y);
    o.z = (a.z + b.z) + (c.z + d.z);
    o.w = (a.w + b.w) + (c.w + d.w);
    ((float4*)G0)[i] = o;
}

// ---------------- edge aggregation (gather-sum over sorted in-edges) ----------------
__global__ __launch_bounds__(128) void k_agg0(
    const float* __restrict__ G0, const int* __restrict__ starts, const int* __restrict__ sorted,
    const float* __restrict__ epsp, const float* __restrict__ bias,
    const float* __restrict__ bg, const float* __restrict__ bb,
    const float* __restrict__ bm, const float* __restrict__ bv,
    unsigned short* __restrict__ outb)
{
    const int d = blockIdx.x, t = threadIdx.x;
    const float ep = 1.0f + epsp[0];
    float4 own = ((const float4*)(G0 + (size_t)d * HH))[t];
    float sx = 0.f, sy = 0.f, sz = 0.f, sw = 0.f;
    const int e0 = starts[d], e1 = starts[d + 1];
    for (int i = e0; i < e1; ++i) {
        float4 x = ((const float4*)(G0 + (size_t)sorted[i] * HH))[t];
        sx += x.x; sy += x.y; sz += x.z; sw += x.w;
    }
    float4 bi = ((const float4*)bias)[t];
    float4 g4 = ((const float4*)bg)[t];
    float4 b4 = ((const float4*)bb)[t];
    float4 m4 = ((const float4*)bm)[t];
    float4 v4 = ((const float4*)bv)[t];
    float x0 = ep * own.x + sx + bi.x;
    float x1 = ep * own.y + sy + bi.y;
    float x2 = ep * own.z + sz + bi.z;
    float x3 = ep * own.w + sw + bi.w;
    x0 = fmaxf((x0 - m4.x) * rsqrtf(v4.x + 1e-5f) * g4.x + b4.x, 0.f);
    x1 = fmaxf((x1 - m4.y) * rsqrtf(v4.y + 1e-5f) * g4.y + b4.y, 0.f);
    x2 = fmaxf((x2 - m4.z) * rsqrtf(v4.z + 1e-5f) * g4.z + b4.z, 0.f);
    x3 = fmaxf((x3 - m4.w) * rsqrtf(v4.w + 1e-5f) * g4.w + b4.w, 0.f);
    ushort4 o; o.x = f2bf(x0); o.y = f2bf(x1); o.z = f2bf(x2); o.w = f2bf(x3);
    ((ushort4*)(outb + (size_t)d * HH))[t] = o;
}

__global__ __launch_bounds__(128) void k_aggL(
    const float* __restrict__ hsrc, const int* __restrict__ starts, const int* __restrict__ sorted,
    const float* __restrict__ epsp, unsigned short* __restrict__ outb)
{
    const int d = blockIdx.x, t = threadIdx.x;
    const float ep = 1.0f + epsp[0];
    float4 own = ((const float4*)(hsrc + (size_t)d * HH))[t];
    float sx = 0.f, sy = 0.f, sz = 0.f, sw = 0.f;
    const int e0 = starts[d], e1 = starts[d + 1];
    for (int i = e0; i < e1; ++i) {
        float4 x = ((const float4*)(hsrc + (size_t)sorted[i] * HH))[t];
        sx += x.x; sy += x.y; sz += x.z; sw += x.w;
    }
    ushort4 o;
    o.x = f2bf(ep * own.x + sx);
    o.y = f2bf(ep * own.y + sy);
    o.z = f2bf(ep * own.z + sz);
    o.w = f2bf(ep * own.w + sw);
    ((ushort4*)(outb + (size_t)d * HH))[t] = o;
}

// ---------------- readout: partial dot products over the 4 hidden reps ----------------
__global__ __launch_bounds__(256) void k_dotR(const float* __restrict__ h,
                                              const float* __restrict__ WpR,
                                              float* __restrict__ part) {
    const int L = blockIdx.y;
    const float* v = h + (size_t)L * NN * HH;
    const float* w = WpR + (size_t)L * NN * HH * 2;
    const long n4 = (long)NN * HH / 4;
    long i = blockIdx.x * 256L + threadIdx.x;
    const long stride = (long)gridDim.x * 256L;
    float a0 = 0.f, a1 = 0.f;
    for (; i < n4; i += stride) {
        float4 x = ((const float4*)v)[i];
        float4 wA = ((const float4*)w)[2 * i];
        float4 wB = ((const float4*)w)[2 * i + 1];
        a0 += x.x * wA.x + x.y * wA.z + x.z * wB.x + x.w * wB.z;
        a1 += x.x * wA.y + x.y * wA.w + x.z * wB.y + x.w * wB.w;
    }
    __shared__ float s0[256], s1[256];
    int t = threadIdx.x;
    s0[t] = a0; s1[t] = a1;
    __syncthreads();
    for (int s = 128; s > 0; s >>= 1) {
        if (t < s) { s0[t] += s0[t + s]; s1[t] += s1[t + s]; }
        __syncthreads();
    }
    if (t == 0) {
        const int slot = 2048 + L * 256 + blockIdx.x;
        part[2 * slot] = s0[0]; part[2 * slot + 1] = s1[0];
    }
}

__global__ __launch_bounds__(256) void k_final(const float* __restrict__ part, int nslot,
                                               const float* __restrict__ bp0, const float* __restrict__ bpR,
                                               float* __restrict__ out) {
    __shared__ float s0[256], s1[256];
    int t = threadIdx.x;
    float a0 = 0.f, a1 = 0.f;
    for (int i = t; i < nslot; i += 256) { a0 += part[2 * i]; a1 += part[2 * i + 1]; }
    s0[t] = a0; s1[t] = a1;
    __syncthreads();
    for (int s = 128; s > 0; s >>= 1) {
        if (t < s) { s0[t] += s0[t + s]; s1[t] += s1[t + s]; }
        __syncthreads();
    }
    if (t == 0) {
        out[0] = s0[0] + bp0[0] + bpR[0] + bpR[2] + bpR[4] + bpR[6];
        out[1] = s1[0] + bp0[1] + bpR[1] + bpR[3] + bpR[5] + bpR[7];
    }
}

extern "C" void kernel_launch(void* const* d_in, const int* in_sizes, int n_in,
                              void* d_out, int out_size, void* d_ws, size_t ws_size,
                              hipStream_t stream)
{
    const float* feat = (const float*)d_in[0];
    const int*   esrc = (const int*)d_in[1];
    const int*   edst = (const int*)d_in[2];
    const float* eps0 = (const float*)d_in[3];
    const float* W0a  = (const float*)d_in[4];
    const float* b0a  = (const float*)d_in[5];
    const float* W0b  = (const float*)d_in[6];
    const float* b0b  = (const float*)d_in[7];
    const float* bn0a_g = (const float*)d_in[8];
    const float* bn0a_b = (const float*)d_in[9];
    const float* bn0a_m = (const float*)d_in[10];
    const float* bn0a_v = (const float*)d_in[11];
    const float* bnA0_g = (const float*)d_in[12];
    const float* bnA0_b = (const float*)d_in[13];
    const float* bnA0_m = (const float*)d_in[14];
    const float* bnA0_v = (const float*)d_in[15];
    const float* bnO0_g = (const float*)d_in[16];
    const float* bnO0_b = (const float*)d_in[17];
    const float* bnO0_m = (const float*)d_in[18];
    const float* bnO0_v = (const float*)d_in[19];
    const float* epsR = (const float*)d_in[20];
    const float* WRa  = (const float*)d_in[21];
    const float* bRa  = (const float*)d_in[22];
    const float* WRb  = (const float*)d_in[23];
    const float* bRb  = (const float*)d_in[24];
    const float* bnRa_g = (const float*)d_in[25];
    const float* bnRa_b = (const float*)d_in[26];
    const float* bnRa_m = (const float*)d_in[27];
    const float* bnRa_v = (const float*)d_in[28];
    const float* bnAR_g = (const float*)d_in[29];
    const float* bnAR_b = (const float*)d_in[30];
    const float* bnAR_m = (const float*)d_in[31];
    const float* bnAR_v = (const float*)d_in[32];
    const float* bnOR_g = (const float*)d_in[33];
    const float* bnOR_b = (const float*)d_in[34];
    const float* bnOR_m = (const float*)d_in[35];
    const float* bnOR_v = (const float*)d_in[36];
    const float* Wp0 = (const float*)d_in[37];
    const float* bp0 = (const float*)d_in[38];
    const float* WpR = (const float*)d_in[39];
    const float* bpR = (const float*)d_in[40];
    float* out = (float*)d_out;

    char* ws = (char*)d_ws;
    const size_t MB = 1024 * 1024;
    int*   cnt    = (int*)(ws + 0x00000);
    int*   starts = (int*)(ws + 0x10000);
    int*   cursor = (int*)(ws + 0x20000);
    int*   sorted = (int*)(ws + 0x30000);     // 256 KiB
    float* part   = (float*)(ws + 0x70000);   // 3072*2 f32
    unsigned short* featb = (unsigned short*)(ws + 1 * MB);    // [4096][4096] bf16, 32 MiB
    unsigned short* w0at  = (unsigned short*)(ws + 33 * MB);   // [512][4096] bf16, 4 MiB
    unsigned short* wt    = (unsigned short*)(ws + 37 * MB);   // 7 x [512][512] bf16
    float* G0 = (float*)(ws + 41 * MB);                        // [4096][512] f32
    unsigned short* xb = (unsigned short*)(ws + 49 * MB);      // [4096][512] bf16
    unsigned short* yb = (unsigned short*)(ws + 53 * MB);      // [4096][512] bf16
    float* h = (float*)(ws + 57 * MB);                         // 4 x [4096][512] f32
    float* pbuf = (float*)(ws + 57 * MB);                      // split-K partials alias h (dead before h0 write)

    // ---- edge sort ----
    hipMemsetAsync(ws, 0, 0x30000, stream);
    k_hist<<<EE / 256, 256, 0, stream>>>(edst, cnt);
    k_scan<<<1, 256, 0, stream>>>(cnt, starts);
    k_scatter<<<EE / 256, 256, 0, stream>>>(esrc, edst, starts, cursor, sorted);
    k_binsort<<<NN / 256, 256, 0, stream>>>(starts, sorted);

    // ---- precision prep (+ fused feat.Wp0 readout dot) ----
    k_cvtdot0<<<2048, 256, 0, stream>>>(feat, Wp0, featb, part);
    k_transcvt<<<dim3(NN / 32, HH / 32), 256, 0, stream>>>(W0a, w0at, NN, HH);
    k_transcvt7<<<dim3(HH / 32, HH / 32, 7), 256, 0, stream>>>(W0b, WRa, WRb, wt);

    // ---- layer 0 (reassociated: G0 = feat@W0a first, then aggregate) ----
    k_gemm<0, 128><<<dim3(32, 4, 4), 256, 0, stream>>>(featb, w0at, NN, HH, NN,
        nullptr, nullptr, nullptr, nullptr, nullptr, nullptr, nullptr, nullptr, nullptr,
        pbuf, nullptr);
    k_red4<<<2048, 256, 0, stream>>>(pbuf, G0);
    k_agg0<<<NN, 128, 0, stream>>>(G0, starts, sorted, eps0, b0a,
                                   bn0a_g, bn0a_b, bn0a_m, bn0a_v, xb);
    k_gemm<2, 64><<<dim3(32, 8), 256, 0, stream>>>(xb, wt, NN, HH, HH,
        b0b, bnA0_g, bnA0_b, bnA0_m, bnA0_v, bnO0_g, bnO0_b, bnO0_m, bnO0_v,
        h, nullptr);

    // ---- layers 1..3 ----
    for (int i = 0; i < 3; ++i) {
        const float* hp = h + (size_t)i * NN * HH;
        float* hn = h + (size_t)(i + 1) * NN * HH;
        k_aggL<<<NN, 128, 0, stream>>>(hp, starts, sorted, epsR + i, xb);
        k_gemm<1, 64><<<dim3(32, 8), 256, 0, stream>>>(xb, wt + (size_t)(1 + i) * HH * HH, NN, HH, HH,
            bRa + (size_t)i * HH,
            bnRa_g + (size_t)i * HH, bnRa_b + (size_t)i * HH, bnRa_m + (size_t)i * HH, bnRa_v + (size_t)i * HH,
            nullptr, nullptr, nullptr, nullptr,
            nullptr, yb);
        k_gemm<2, 64><<<dim3(32, 8), 256, 0, stream>>>(yb, wt + (size_t)(4 + i) * HH * HH, NN, HH, HH,
            bRb + (size_t)i * HH,
            bnAR_g + (size_t)i * HH, bnAR_b + (size_t)i * HH, bnAR_m + (size_t)i * HH, bnAR_v + (size_t)i * HH,
            bnOR_g + (size_t)i * HH, bnOR_b + (size_t)i * HH, bnOR_m + (size_t)i * HH, bnOR_v + (size_t)i * HH,
            hn, nullptr);
    }

    // ---- jumping-knowledge readout (h dots merged into one launch) ----
    k_dotR<<<dim3(256, 4), 256, 0, stream>>>(h, WpR, part);
    k_final<<<1, 256, 0, stream>>>(part, 2048 + 4 * 256, bp0, bpR, out);
}